// Round 1
// baseline (18601.305 us; speedup 1.0000x reference)
//
#include <hip/hip_runtime.h>
#include <cstdint>
#include <cstddef>

typedef _Float16 half8  __attribute__((ext_vector_type(8)));
typedef float    floatx4 __attribute__((ext_vector_type(4)));

#define T_STEPS 1500
#define BATCH   16
#define FDIM    440
#define FPAD    448
#define HDIM    512
#define MROWS   (T_STEPS*BATCH)   /* 24000 */
#define NGATES  1024
#define NWG     16

// ---------------- small utility kernels ----------------

__global__ __launch_bounds__(256) void zero_k(uint32_t* p, int n) {
    int i = blockIdx.x * 256 + threadIdx.x;
    if (i < n) p[i] = 0u;
}

// one block per row: dst[row][0..dst_cols) = f16(src[row][0..src_cols)) zero-padded
__global__ __launch_bounds__(256) void cvt_pad(const float* __restrict__ src,
                                               _Float16* __restrict__ dst,
                                               int src_cols, int dst_cols) {
    int row = blockIdx.x;
    for (int k = threadIdx.x; k < dst_cols; k += 256) {
        float v = (k < src_cols) ? src[(size_t)row * src_cols + k] : 0.f;
        dst[(size_t)row * dst_cols + k] = (_Float16)v;
    }
}

__global__ __launch_bounds__(256) void cat2(const float* __restrict__ a,
                                            const float* __restrict__ b,
                                            float* __restrict__ dst) {
    int i = blockIdx.x * 256 + threadIdx.x;
    if (i < 1024) dst[i] = (i < 512) ? a[i] : b[i - 512];
}

// ---------------- GEMM: C[M,1024] = A[M,Kp] * B[1024,Kp]^T + bias ----------------
// fp16 inputs, fp32 accum. 128x128 tile, BK=32, 4 waves of 64x64.

__global__ __launch_bounds__(256) void gemm_tn(const _Float16* __restrict__ A,
                                               const _Float16* __restrict__ B,
                                               const float* __restrict__ bias,
                                               float* __restrict__ C32,
                                               _Float16* __restrict__ C16,
                                               int M, int Kp, int use_f32) {
    __shared__ _Float16 As[128 * 40];   // row stride 40 f16 = 80B (16B aligned, mild bank alias)
    __shared__ _Float16 Bs[128 * 40];

    const int tid = threadIdx.x;
    const int wv = tid >> 6, l = tid & 63, q = l >> 4, c = l & 15;
    const int wr = wv >> 1, wc = wv & 1;
    const int m0 = blockIdx.y * 128, n0 = blockIdx.x * 128;

    floatx4 acc[4][4] = {};

    for (int kt = 0; kt < Kp; kt += 32) {
        // stage 128x32 of A and B (each thread: 2 slots x {A,B}, 16B each)
#pragma unroll
        for (int i = 0; i < 2; ++i) {
            int s = tid + i * 256;
            int row = s >> 2, qq = s & 3;
            uint4 va = {0u, 0u, 0u, 0u};
            int gm = m0 + row;
            if (gm < M) va = *(const uint4*)(A + (size_t)gm * Kp + kt + qq * 8);
            *(uint4*)(As + row * 40 + qq * 8) = va;
            uint4 vb = *(const uint4*)(B + (size_t)(n0 + row) * Kp + kt + qq * 8);
            *(uint4*)(Bs + row * 40 + qq * 8) = vb;
        }
        __syncthreads();

        half8 af[4], bf[4];
#pragma unroll
        for (int mi = 0; mi < 4; ++mi)
            af[mi] = *(const half8*)(As + (wr * 64 + mi * 16 + c) * 40 + q * 8);
#pragma unroll
        for (int ni = 0; ni < 4; ++ni)
            bf[ni] = *(const half8*)(Bs + (wc * 64 + ni * 16 + c) * 40 + q * 8);
#pragma unroll
        for (int mi = 0; mi < 4; ++mi)
#pragma unroll
            for (int ni = 0; ni < 4; ++ni)
                acc[mi][ni] = __builtin_amdgcn_mfma_f32_16x16x32_f16(af[mi], bf[ni], acc[mi][ni], 0, 0, 0);
        __syncthreads();
    }

#pragma unroll
    for (int ni = 0; ni < 4; ++ni) {
        int n = n0 + wc * 64 + ni * 16 + c;
        float bv = bias[n];
#pragma unroll
        for (int mi = 0; mi < 4; ++mi) {
#pragma unroll
            for (int r = 0; r < 4; ++r) {
                int gm = m0 + wr * 64 + mi * 16 + q * 4 + r;
                if (gm < M) {
                    float v = acc[mi][ni][r] + bv;
                    if (use_f32) C32[(size_t)gm * NGATES + n] = v;
                    else         C16[(size_t)gm * NGATES + n] = (_Float16)v;
                }
            }
        }
    }
}

// ---------------- persistent liGRU scan ----------------
// 16 WGs x 256 thr. WG w owns features [w*32, w*32+32).
// Waves 0,1: Uz tiles (gate z); waves 2,3: Uh tiles (gate h).
// U fragments live in registers for the whole kernel (64 VGPR/wave).
// h ping-pongs through a global fp16 buffer; device-scope barrier per step.

__global__ __launch_bounds__(256) void ligru_scan(const float* __restrict__ gates32,
                                                  const _Float16* __restrict__ gates16,
                                                  const _Float16* __restrict__ Uz,
                                                  const _Float16* __restrict__ Uh,
                                                  _Float16* __restrict__ hbuf,      // [2][16*512] f16
                                                  unsigned int* __restrict__ counter,
                                                  _Float16* __restrict__ out16,     // h1 (layer0) or null
                                                  float* __restrict__ out32,        // d_out (layer1) or null
                                                  int use_gf32) {
    const int tid = threadIdx.x, wg = blockIdx.x;
    const int wv = tid >> 6, l = tid & 63, q = l >> 4, c = l & 15;
    const int gate = wv >> 1, ti = wv & 1;

    // ---- load persistent U fragments: B[k][n] = U[n][k], n = lane&15 row ----
    const _Float16* U = (gate == 0) ? Uz : Uh;
    const int urow = wg * 32 + ti * 16 + c;
    half8 u[16];
#pragma unroll
    for (int ks = 0; ks < 16; ++ks)
        u[ks] = *(const half8*)(U + (size_t)urow * HDIM + ks * 32 + q * 8);

    __shared__ float accS[2][2][16][16];   // [gate][tile][feat15][batch]

    // epilogue role: thread -> (batch, feature pair)
    const int eb  = tid >> 4;          // batch 0..15
    const int enl = (tid & 15) * 2;    // local feature (even) 0..30
    const int en  = wg * 32 + enl;     // global feature
    float h0 = 0.f, h1 = 0.f;          // persistent fp32 state

    int p = 0;
    for (int t = 0; t < T_STEPS; ++t) {
        const int row = t * BATCH + eb;

        // issue gate-input loads early (independent of h barrier)
        float whv0, whv1, wzv0, wzv1;
        if (use_gf32) {
            float2 a2 = *(const float2*)(gates32 + (size_t)row * NGATES + en);
            float2 b2 = *(const float2*)(gates32 + (size_t)row * NGATES + 512 + en);
            whv0 = a2.x; whv1 = a2.y; wzv0 = b2.x; wzv1 = b2.y;
        } else {
            union { uint32_t u; _Float16 h[2]; } ua, ub;
            ua.u = *(const uint32_t*)(gates16 + (size_t)row * NGATES + en);
            ub.u = *(const uint32_t*)(gates16 + (size_t)row * NGATES + 512 + en);
            whv0 = (float)ua.h[0]; whv1 = (float)ua.h[1];
            wzv0 = (float)ub.h[0]; wzv1 = (float)ub.h[1];
        }

        // ---- MFMA: A[m][k] = h_prev[batch=lane&15][k] ----
        const _Float16* hb = hbuf + (size_t)p * (BATCH * HDIM);
        half8 a[16];
#pragma unroll
        for (int ks = 0; ks < 16; ++ks)
            a[ks] = *(const half8*)(hb + (size_t)c * HDIM + ks * 32 + q * 8);
        floatx4 acc = {0.f, 0.f, 0.f, 0.f};
#pragma unroll
        for (int ks = 0; ks < 16; ++ks)
            acc = __builtin_amdgcn_mfma_f32_16x16x32_f16(a[ks], u[ks], acc, 0, 0, 0);

        // D layout: col=lane&15 (feature), row=q*4+r (batch)
        *(floatx4*)&accS[gate][ti][c][q * 4] = acc;
        __syncthreads();

        // ---- elementwise update for (eb, en), (eb, en+1) ----
        const int t0 = enl >> 4, f0 = enl & 15;
        float Sz0 = accS[0][t0][f0][eb],     Sh0 = accS[1][t0][f0][eb];
        float Sz1 = accS[0][t0][f0 + 1][eb], Sh1 = accS[1][t0][f0 + 1][eb];

        float z0 = 1.f / (1.f + __expf(-(wzv0 + Sz0)));
        float z1 = 1.f / (1.f + __expf(-(wzv1 + Sz1)));
        float hc0 = fmaxf(0.f, whv0 + Sh0);
        float hc1 = fmaxf(0.f, whv1 + Sh1);
        h0 = z0 * h0 + (1.f - z0) * hc0;
        h1 = z1 * h1 + (1.f - z1) * hc1;

        union { _Float16 h[2]; uint32_t u; } pk;
        pk.h[0] = (_Float16)h0; pk.h[1] = (_Float16)h1;
        *(uint32_t*)(hbuf + (size_t)(p ^ 1) * (BATCH * HDIM) + eb * HDIM + en) = pk.u;
        if (out16) *(uint32_t*)(out16 + (size_t)row * HDIM + en) = pk.u;
        if (out32) { float2 o; o.x = h0; o.y = h1;
                     *(float2*)(out32 + (size_t)row * HDIM + en) = o; }

        // ---- device-scope barrier (monotonic counter) ----
        __builtin_amdgcn_fence(__ATOMIC_RELEASE, "agent");   // waitcnt + L2 writeback
        __syncthreads();
        if (tid == 0) {
            __hip_atomic_fetch_add(counter, 1u, __ATOMIC_RELAXED, __HIP_MEMORY_SCOPE_AGENT);
            const unsigned tgt = (unsigned)(NWG * (t + 1));
            while (__hip_atomic_load(counter, __ATOMIC_RELAXED, __HIP_MEMORY_SCOPE_AGENT) < tgt) { }
        }
        __syncthreads();
        __builtin_amdgcn_fence(__ATOMIC_ACQUIRE, "agent");   // L1/L2 invalidate
        p ^= 1;
    }
}

// ---------------- host ----------------

extern "C" void kernel_launch(void* const* d_in, const int* in_sizes, int n_in,
                              void* d_out, int out_size, void* d_ws, size_t ws_size,
                              hipStream_t stream) {
    const float* x   = (const float*)d_in[0];
    const float* Wh0 = (const float*)d_in[1];
    const float* bh0 = (const float*)d_in[2];
    const float* Wz0 = (const float*)d_in[3];
    const float* bz0 = (const float*)d_in[4];
    const float* Uh0 = (const float*)d_in[5];
    const float* Uz0 = (const float*)d_in[6];
    const float* Wh1 = (const float*)d_in[7];
    const float* bh1 = (const float*)d_in[8];
    const float* Wz1 = (const float*)d_in[9];
    const float* bz1 = (const float*)d_in[10];
    const float* Uh1 = (const float*)d_in[11];
    const float* Uz1 = (const float*)d_in[12];
    float* out = (float*)d_out;

    uint8_t* ws = (uint8_t*)d_ws;
    size_t off = 0;
    auto alloc = [&](size_t b) { size_t o = off; off += (b + 255) & ~(size_t)255; return o; };

    size_t o_ctr  = alloc(512);                                   // 2 counters (cache-line apart)
    size_t o_hbuf = alloc(2 * 2 * BATCH * HDIM * sizeof(_Float16)); // layer0 + layer1 ping-pong
    size_t o_Uz0  = alloc((size_t)HDIM * HDIM * 2);
    size_t o_Uh0  = alloc((size_t)HDIM * HDIM * 2);
    size_t o_Uz1  = alloc((size_t)HDIM * HDIM * 2);
    size_t o_Uh1  = alloc((size_t)HDIM * HDIM * 2);
    size_t o_Wc0  = alloc((size_t)NGATES * FPAD * 2);
    size_t o_Wc1  = alloc((size_t)NGATES * HDIM * 2);
    size_t o_b0   = alloc(1024 * 4);
    size_t o_b1   = alloc(1024 * 4);
    size_t o_xb   = alloc((size_t)MROWS * FPAD * 2);
    size_t o_h1   = alloc((size_t)MROWS * HDIM * 2);
    size_t o_g    = off;
    size_t need32 = off + (size_t)MROWS * NGATES * 4;
    int use_gf32 = (ws_size >= need32) ? 1 : 0;   // fall back to f16 gates if scratch is tight

    _Float16* XB  = (_Float16*)(ws + o_xb);
    _Float16* WC0 = (_Float16*)(ws + o_Wc0);
    _Float16* WC1 = (_Float16*)(ws + o_Wc1);
    _Float16* UZ0 = (_Float16*)(ws + o_Uz0);
    _Float16* UH0 = (_Float16*)(ws + o_Uh0);
    _Float16* UZ1 = (_Float16*)(ws + o_Uz1);
    _Float16* UH1 = (_Float16*)(ws + o_Uh1);
    _Float16* H1B = (_Float16*)(ws + o_h1);
    float*    B0  = (float*)(ws + o_b0);
    float*    B1  = (float*)(ws + o_b1);
    float*    G32 = (float*)(ws + o_g);
    _Float16* G16 = (_Float16*)(ws + o_g);
    _Float16* HB0 = (_Float16*)(ws + o_hbuf);
    _Float16* HB1 = HB0 + 2 * BATCH * HDIM;
    unsigned int* CTR0 = (unsigned int*)(ws + o_ctr);
    unsigned int* CTR1 = (unsigned int*)(ws + o_ctr + 256);

    // zero counters + both h ping-pong buffers (ws is poisoned 0xAA each call)
    zero_k<<<65, 256, 0, stream>>>((uint32_t*)(ws + o_ctr), (int)((512 + 2 * 2 * BATCH * HDIM * 2) / 4));

    // fp32 -> fp16 conversions (with K padding)
    cvt_pad<<<MROWS, 256, 0, stream>>>(x, XB, FDIM, FPAD);
    cvt_pad<<<512, 256, 0, stream>>>(Wh0, WC0,              FDIM, FPAD);
    cvt_pad<<<512, 256, 0, stream>>>(Wz0, WC0 + 512 * FPAD, FDIM, FPAD);
    cvt_pad<<<512, 256, 0, stream>>>(Wh1, WC1,              HDIM, HDIM);
    cvt_pad<<<512, 256, 0, stream>>>(Wz1, WC1 + 512 * HDIM, HDIM, HDIM);
    cvt_pad<<<512, 256, 0, stream>>>(Uz0, UZ0, HDIM, HDIM);
    cvt_pad<<<512, 256, 0, stream>>>(Uh0, UH0, HDIM, HDIM);
    cvt_pad<<<512, 256, 0, stream>>>(Uz1, UZ1, HDIM, HDIM);
    cvt_pad<<<512, 256, 0, stream>>>(Uh1, UH1, HDIM, HDIM);
    cat2<<<4, 256, 0, stream>>>(bh0, bz0, B0);
    cat2<<<4, 256, 0, stream>>>(bh1, bz1, B1);

    dim3 gg(NGATES / 128, (MROWS + 127) / 128);

    // layer 0
    gemm_tn<<<gg, 256, 0, stream>>>(XB, WC0, B0, G32, G16, MROWS, FPAD, use_gf32);
    ligru_scan<<<NWG, 256, 0, stream>>>(G32, G16, UZ0, UH0, HB0, CTR0, H1B, nullptr, use_gf32);
    // layer 1
    gemm_tn<<<gg, 256, 0, stream>>>(H1B, WC1, B1, G32, G16, MROWS, HDIM, use_gf32);
    ligru_scan<<<NWG, 256, 0, stream>>>(G32, G16, UZ1, UH1, HB1, CTR1, nullptr, out, use_gf32);

    (void)in_sizes; (void)n_in; (void)out_size;
}

// Round 2
// 17944.537 us; speedup vs baseline: 1.0366x; 1.0366x over previous
//
#include <hip/hip_runtime.h>
#include <cstdint>
#include <cstddef>

typedef _Float16 half8  __attribute__((ext_vector_type(8)));
typedef float    floatx4 __attribute__((ext_vector_type(4)));

#define T_STEPS 1500
#define BATCH   16
#define FDIM    440
#define FPAD    448
#define HDIM    512
#define MROWS   (T_STEPS*BATCH)   /* 24000 */
#define NGATES  1024
#define NWG     16

// ---------------- small utility kernels ----------------

__global__ __launch_bounds__(256) void zero_k(uint32_t* p, int n) {
    int i = blockIdx.x * 256 + threadIdx.x;
    if (i < n) p[i] = 0u;
}

// one block per row: dst[row][0..dst_cols) = f16(src[row][0..src_cols)) zero-padded
__global__ __launch_bounds__(256) void cvt_pad(const float* __restrict__ src,
                                               _Float16* __restrict__ dst,
                                               int src_cols, int dst_cols) {
    int row = blockIdx.x;
    for (int k = threadIdx.x; k < dst_cols; k += 256) {
        float v = (k < src_cols) ? src[(size_t)row * src_cols + k] : 0.f;
        dst[(size_t)row * dst_cols + k] = (_Float16)v;
    }
}

__global__ __launch_bounds__(256) void cat2(const float* __restrict__ a,
                                            const float* __restrict__ b,
                                            float* __restrict__ dst) {
    int i = blockIdx.x * 256 + threadIdx.x;
    if (i < 1024) dst[i] = (i < 512) ? a[i] : b[i - 512];
}

// ---------------- GEMM: C[M,1024] = A[M,Kp] * B[1024,Kp]^T + bias ----------------
// fp16 inputs, fp32 accum. 128x128 tile, BK=32, 4 waves of 64x64.

__global__ __launch_bounds__(256) void gemm_tn(const _Float16* __restrict__ A,
                                               const _Float16* __restrict__ B,
                                               const float* __restrict__ bias,
                                               float* __restrict__ C32,
                                               _Float16* __restrict__ C16,
                                               int M, int Kp, int use_f32) {
    __shared__ _Float16 As[128 * 40];   // row stride 40 f16 = 80B (16B aligned, mild bank alias)
    __shared__ _Float16 Bs[128 * 40];

    const int tid = threadIdx.x;
    const int wv = tid >> 6, l = tid & 63, q = l >> 4, c = l & 15;
    const int wr = wv >> 1, wc = wv & 1;
    const int m0 = blockIdx.y * 128, n0 = blockIdx.x * 128;

    floatx4 acc[4][4] = {};

    for (int kt = 0; kt < Kp; kt += 32) {
        // stage 128x32 of A and B (each thread: 2 slots x {A,B}, 16B each)
#pragma unroll
        for (int i = 0; i < 2; ++i) {
            int s = tid + i * 256;
            int row = s >> 2, qq = s & 3;
            uint4 va = {0u, 0u, 0u, 0u};
            int gm = m0 + row;
            if (gm < M) va = *(const uint4*)(A + (size_t)gm * Kp + kt + qq * 8);
            *(uint4*)(As + row * 40 + qq * 8) = va;
            uint4 vb = *(const uint4*)(B + (size_t)(n0 + row) * Kp + kt + qq * 8);
            *(uint4*)(Bs + row * 40 + qq * 8) = vb;
        }
        __syncthreads();

        half8 af[4], bf[4];
#pragma unroll
        for (int mi = 0; mi < 4; ++mi)
            af[mi] = *(const half8*)(As + (wr * 64 + mi * 16 + c) * 40 + q * 8);
#pragma unroll
        for (int ni = 0; ni < 4; ++ni)
            bf[ni] = *(const half8*)(Bs + (wc * 64 + ni * 16 + c) * 40 + q * 8);
#pragma unroll
        for (int mi = 0; mi < 4; ++mi)
#pragma unroll
            for (int ni = 0; ni < 4; ++ni)
                acc[mi][ni] = __builtin_amdgcn_mfma_f32_16x16x32_f16(af[mi], bf[ni], acc[mi][ni], 0, 0, 0);
        __syncthreads();
    }

#pragma unroll
    for (int ni = 0; ni < 4; ++ni) {
        int n = n0 + wc * 64 + ni * 16 + c;
        float bv = bias[n];
#pragma unroll
        for (int mi = 0; mi < 4; ++mi) {
#pragma unroll
            for (int r = 0; r < 4; ++r) {
                int gm = m0 + wr * 64 + mi * 16 + q * 4 + r;
                if (gm < M) {
                    float v = acc[mi][ni][r] + bv;
                    if (use_f32) C32[(size_t)gm * NGATES + n] = v;
                    else         C16[(size_t)gm * NGATES + n] = (_Float16)v;
                }
            }
        }
    }
}

// ---------------- persistent liGRU scan ----------------
// 16 WGs x 256 thr. WG w owns features [w*32, w*32+32).
// Waves 0,1: Uz tiles (gate z); waves 2,3: Uh tiles (gate h).
// U fragments live in registers for the whole kernel (pinned via opaque asm;
// __launch_bounds__(256,1) so the allocator doesn't rematerialize them).
// h ping-pongs through a global fp16 buffer with RELAXED/AGENT atomics
// (sc0 sc1 flagged ops -> coherence point; NO buffer_wbl2/buffer_inv fences).

__global__ __launch_bounds__(256, 1) void ligru_scan(const float* __restrict__ gates32,
                                                     const _Float16* __restrict__ gates16,
                                                     const _Float16* __restrict__ Uz,
                                                     const _Float16* __restrict__ Uh,
                                                     _Float16* __restrict__ hbuf,      // [2][16*512] f16
                                                     unsigned int* __restrict__ counter,
                                                     _Float16* __restrict__ out16,     // h1 (layer0) or null
                                                     float* __restrict__ out32,        // d_out (layer1) or null
                                                     int use_gf32) {
    const int tid = threadIdx.x, wg = blockIdx.x;
    const int wv = tid >> 6, l = tid & 63, q = l >> 4, c = l & 15;
    const int gate = wv >> 1, ti = wv & 1;

    // ---- load persistent U fragments: B[k][n] = U[n][k], n = lane&15 row ----
    const _Float16* U = (gate == 0) ? Uz : Uh;
    const int urow = wg * 32 + ti * 16 + c;
    half8 u[16];
#pragma unroll
    for (int ks = 0; ks < 16; ++ks)
        u[ks] = *(const half8*)(U + (size_t)urow * HDIM + ks * 32 + q * 8);
    // Opaque redefinition: values now originate from asm -> loads cannot be
    // sunk/rematerialized inside the t-loop.
#pragma unroll
    for (int ks = 0; ks < 16; ++ks)
        asm volatile("" : "+v"(u[ks]));

    __shared__ float accS[2][2][16][16];   // [gate][tile][feat15][batch]

    // epilogue role: thread -> (batch, feature pair)
    const int eb  = tid >> 4;          // batch 0..15
    const int enl = (tid & 15) * 2;    // local feature (even) 0..30
    const int en  = wg * 32 + enl;     // global feature
    float h0 = 0.f, h1 = 0.f;          // persistent fp32 state

    // gates double-buffer: load step-t gates one iteration early
    auto gload = [&](int t, float& w0, float& w1, float& z0, float& z1) {
        const int row = t * BATCH + eb;
        if (use_gf32) {
            float2 a2 = *(const float2*)(gates32 + (size_t)row * NGATES + en);
            float2 b2 = *(const float2*)(gates32 + (size_t)row * NGATES + 512 + en);
            w0 = a2.x; w1 = a2.y; z0 = b2.x; z1 = b2.y;
        } else {
            union { uint32_t u; _Float16 h[2]; } ua, ub;
            ua.u = *(const uint32_t*)(gates16 + (size_t)row * NGATES + en);
            ub.u = *(const uint32_t*)(gates16 + (size_t)row * NGATES + 512 + en);
            w0 = (float)ua.h[0]; w1 = (float)ua.h[1];
            z0 = (float)ub.h[0]; z1 = (float)ub.h[1];
        }
    };

    float whv0, whv1, wzv0, wzv1;
    gload(0, whv0, whv1, wzv0, wzv1);

    int p = 0;
    for (int t = 0; t < T_STEPS; ++t) {
        // issue NEXT step's gate loads early (independent of everything here)
        float nw0 = 0.f, nw1 = 0.f, nz0 = 0.f, nz1 = 0.f;
        if (t + 1 < T_STEPS) gload(t + 1, nw0, nw1, nz0, nz1);

        // ---- A fragment: A[m][k] = h_prev[batch=lane&15][k], via agent-scope
        //      (sc-flagged) loads that bypass the non-coherent L1/L2 ----
        const unsigned long long* hq =
            (const unsigned long long*)(hbuf + (size_t)p * (BATCH * HDIM) + (size_t)c * HDIM);
        half8 a[16];
#pragma unroll
        for (int ks = 0; ks < 16; ++ks) {
            union { unsigned long long q[2]; half8 h; } uu;
            uu.q[0] = __hip_atomic_load(hq + ks * 8 + q * 2,     __ATOMIC_RELAXED, __HIP_MEMORY_SCOPE_AGENT);
            uu.q[1] = __hip_atomic_load(hq + ks * 8 + q * 2 + 1, __ATOMIC_RELAXED, __HIP_MEMORY_SCOPE_AGENT);
            a[ks] = uu.h;
        }

        floatx4 acc = {0.f, 0.f, 0.f, 0.f};
#pragma unroll
        for (int ks = 0; ks < 16; ++ks)
            acc = __builtin_amdgcn_mfma_f32_16x16x32_f16(a[ks], u[ks], acc, 0, 0, 0);

        // D layout: col=lane&15 (feature), row=q*4+r (batch)
        *(floatx4*)&accS[gate][ti][c][q * 4] = acc;
        __syncthreads();

        // ---- elementwise update for (eb, en), (eb, en+1) ----
        const int t0 = enl >> 4, f0 = enl & 15;
        float Sz0 = accS[0][t0][f0][eb],     Sh0 = accS[1][t0][f0][eb];
        float Sz1 = accS[0][t0][f0 + 1][eb], Sh1 = accS[1][t0][f0 + 1][eb];

        float z0 = 1.f / (1.f + __expf(-(wzv0 + Sz0)));
        float z1 = 1.f / (1.f + __expf(-(wzv1 + Sz1)));
        float hc0 = fmaxf(0.f, whv0 + Sh0);
        float hc1 = fmaxf(0.f, whv1 + Sh1);
        h0 = z0 * h0 + (1.f - z0) * hc0;
        h1 = z1 * h1 + (1.f - z1) * hc1;

        union { _Float16 h[2]; uint32_t u; } pk;
        pk.h[0] = (_Float16)h0; pk.h[1] = (_Float16)h1;
        // h exchange: agent-scope store (write-through to coherence point)
        __hip_atomic_store((uint32_t*)(hbuf + (size_t)(p ^ 1) * (BATCH * HDIM) + eb * HDIM + en),
                           pk.u, __ATOMIC_RELAXED, __HIP_MEMORY_SCOPE_AGENT);
        const int row = t * BATCH + eb;
        if (out16) *(uint32_t*)(out16 + (size_t)row * HDIM + en) = pk.u;
        if (out32) { float2 o; o.x = h0; o.y = h1;
                     *(float2*)(out32 + (size_t)row * HDIM + en) = o; }

        // ---- device-scope barrier (monotonic counter), no cache fences ----
        __builtin_amdgcn_s_waitcnt(0);   // all h stores ack'd at coherence point
        __syncthreads();
        if (tid == 0) {
            __hip_atomic_fetch_add(counter, 1u, __ATOMIC_RELAXED, __HIP_MEMORY_SCOPE_AGENT);
            const unsigned tgt = (unsigned)(NWG * (t + 1));
            while (__hip_atomic_load(counter, __ATOMIC_RELAXED, __HIP_MEMORY_SCOPE_AGENT) < tgt) { }
        }
        __syncthreads();

        whv0 = nw0; whv1 = nw1; wzv0 = nz0; wzv1 = nz1;
        p ^= 1;
    }
}

// ---------------- host ----------------

extern "C" void kernel_launch(void* const* d_in, const int* in_sizes, int n_in,
                              void* d_out, int out_size, void* d_ws, size_t ws_size,
                              hipStream_t stream) {
    const float* x   = (const float*)d_in[0];
    const float* Wh0 = (const float*)d_in[1];
    const float* bh0 = (const float*)d_in[2];
    const float* Wz0 = (const float*)d_in[3];
    const float* bz0 = (const float*)d_in[4];
    const float* Uh0 = (const float*)d_in[5];
    const float* Uz0 = (const float*)d_in[6];
    const float* Wh1 = (const float*)d_in[7];
    const float* bh1 = (const float*)d_in[8];
    const float* Wz1 = (const float*)d_in[9];
    const float* bz1 = (const float*)d_in[10];
    const float* Uh1 = (const float*)d_in[11];
    const float* Uz1 = (const float*)d_in[12];
    float* out = (float*)d_out;

    uint8_t* ws = (uint8_t*)d_ws;
    size_t off = 0;
    auto alloc = [&](size_t b) { size_t o = off; off += (b + 255) & ~(size_t)255; return o; };

    size_t o_ctr  = alloc(512);                                   // 2 counters (cache-line apart)
    size_t o_hbuf = alloc(2 * 2 * BATCH * HDIM * sizeof(_Float16)); // layer0 + layer1 ping-pong
    size_t o_Uz0  = alloc((size_t)HDIM * HDIM * 2);
    size_t o_Uh0  = alloc((size_t)HDIM * HDIM * 2);
    size_t o_Uz1  = alloc((size_t)HDIM * HDIM * 2);
    size_t o_Uh1  = alloc((size_t)HDIM * HDIM * 2);
    size_t o_Wc0  = alloc((size_t)NGATES * FPAD * 2);
    size_t o_Wc1  = alloc((size_t)NGATES * HDIM * 2);
    size_t o_b0   = alloc(1024 * 4);
    size_t o_b1   = alloc(1024 * 4);
    size_t o_xb   = alloc((size_t)MROWS * FPAD * 2);
    size_t o_h1   = alloc((size_t)MROWS * HDIM * 2);
    size_t o_g    = off;
    size_t need32 = off + (size_t)MROWS * NGATES * 4;
    int use_gf32 = (ws_size >= need32) ? 1 : 0;   // fall back to f16 gates if scratch is tight

    _Float16* XB  = (_Float16*)(ws + o_xb);
    _Float16* WC0 = (_Float16*)(ws + o_Wc0);
    _Float16* WC1 = (_Float16*)(ws + o_Wc1);
    _Float16* UZ0 = (_Float16*)(ws + o_Uz0);
    _Float16* UH0 = (_Float16*)(ws + o_Uh0);
    _Float16* UZ1 = (_Float16*)(ws + o_Uz1);
    _Float16* UH1 = (_Float16*)(ws + o_Uh1);
    _Float16* H1B = (_Float16*)(ws + o_h1);
    float*    B0  = (float*)(ws + o_b0);
    float*    B1  = (float*)(ws + o_b1);
    float*    G32 = (float*)(ws + o_g);
    _Float16* G16 = (_Float16*)(ws + o_g);
    _Float16* HB0 = (_Float16*)(ws + o_hbuf);
    _Float16* HB1 = HB0 + 2 * BATCH * HDIM;
    unsigned int* CTR0 = (unsigned int*)(ws + o_ctr);
    unsigned int* CTR1 = (unsigned int*)(ws + o_ctr + 256);

    // zero counters + both h ping-pong buffers (ws is poisoned 0xAA each call)
    zero_k<<<65, 256, 0, stream>>>((uint32_t*)(ws + o_ctr), (int)((512 + 2 * 2 * BATCH * HDIM * 2) / 4));

    // fp32 -> fp16 conversions (with K padding)
    cvt_pad<<<MROWS, 256, 0, stream>>>(x, XB, FDIM, FPAD);
    cvt_pad<<<512, 256, 0, stream>>>(Wh0, WC0,              FDIM, FPAD);
    cvt_pad<<<512, 256, 0, stream>>>(Wz0, WC0 + 512 * FPAD, FDIM, FPAD);
    cvt_pad<<<512, 256, 0, stream>>>(Wh1, WC1,              HDIM, HDIM);
    cvt_pad<<<512, 256, 0, stream>>>(Wz1, WC1 + 512 * HDIM, HDIM, HDIM);
    cvt_pad<<<512, 256, 0, stream>>>(Uz0, UZ0, HDIM, HDIM);
    cvt_pad<<<512, 256, 0, stream>>>(Uh0, UH0, HDIM, HDIM);
    cvt_pad<<<512, 256, 0, stream>>>(Uz1, UZ1, HDIM, HDIM);
    cvt_pad<<<512, 256, 0, stream>>>(Uh1, UH1, HDIM, HDIM);
    cat2<<<4, 256, 0, stream>>>(bh0, bz0, B0);
    cat2<<<4, 256, 0, stream>>>(bh1, bz1, B1);

    dim3 gg(NGATES / 128, (MROWS + 127) / 128);

    // layer 0
    gemm_tn<<<gg, 256, 0, stream>>>(XB, WC0, B0, G32, G16, MROWS, FPAD, use_gf32);
    ligru_scan<<<NWG, 256, 0, stream>>>(G32, G16, UZ0, UH0, HB0, CTR0, H1B, nullptr, use_gf32);
    // layer 1
    gemm_tn<<<gg, 256, 0, stream>>>(H1B, WC1, B1, G32, G16, MROWS, HDIM, use_gf32);
    ligru_scan<<<NWG, 256, 0, stream>>>(G32, G16, UZ1, UH1, HB1, CTR1, nullptr, out, use_gf32);

    (void)in_sizes; (void)n_in; (void)out_size;
}

// Round 3
// 9154.202 us; speedup vs baseline: 2.0320x; 1.9603x over previous
//
#include <hip/hip_runtime.h>
#include <cstdint>
#include <cstddef>

typedef _Float16 half8  __attribute__((ext_vector_type(8)));
typedef float    floatx4 __attribute__((ext_vector_type(4)));

#define T_STEPS 1500
#define BATCH   16
#define FDIM    440
#define FPAD    448
#define HDIM    512
#define MROWS   (T_STEPS*BATCH)   /* 24000 */
#define NGATES  1024

// Tagged exchange: u64 = (tag32 << 32) | (2 x f16). One step's h state =
// 16 batch x 512 feat = 4096 u64 = 32 KB.
#define EXW     4096              /* u64 words per state snapshot */

// ---------------- small utility kernels ----------------

__global__ __launch_bounds__(256) void cvt_pad(const float* __restrict__ src,
                                               _Float16* __restrict__ dst,
                                               int src_cols, int dst_cols) {
    int row = blockIdx.x;
    for (int k = threadIdx.x; k < dst_cols; k += 256) {
        float v = (k < src_cols) ? src[(size_t)row * src_cols + k] : 0.f;
        dst[(size_t)row * dst_cols + k] = (_Float16)v;
    }
}

__global__ __launch_bounds__(256) void cat2(const float* __restrict__ a,
                                            const float* __restrict__ b,
                                            float* __restrict__ dst) {
    int i = blockIdx.x * 256 + threadIdx.x;
    if (i < 1024) dst[i] = (i < 512) ? a[i] : b[i - 512];
}

// ---------------- GEMM: C[M,1024] = A[M,Kp] * B[1024,Kp]^T + bias (layer 0 gates) ----

__global__ __launch_bounds__(256) void gemm_tn(const _Float16* __restrict__ A,
                                               const _Float16* __restrict__ B,
                                               const float* __restrict__ bias,
                                               float* __restrict__ C32,
                                               _Float16* __restrict__ C16,
                                               int M, int Kp, int use_f32) {
    __shared__ _Float16 As[128 * 40];
    __shared__ _Float16 Bs[128 * 40];

    const int tid = threadIdx.x;
    const int wv = tid >> 6, l = tid & 63, q = l >> 4, c = l & 15;
    const int wr = wv >> 1, wc = wv & 1;
    const int m0 = blockIdx.y * 128, n0 = blockIdx.x * 128;

    floatx4 acc[4][4] = {};

    for (int kt = 0; kt < Kp; kt += 32) {
#pragma unroll
        for (int i = 0; i < 2; ++i) {
            int s = tid + i * 256;
            int row = s >> 2, qq = s & 3;
            uint4 va = {0u, 0u, 0u, 0u};
            int gm = m0 + row;
            if (gm < M) va = *(const uint4*)(A + (size_t)gm * Kp + kt + qq * 8);
            *(uint4*)(As + row * 40 + qq * 8) = va;
            uint4 vb = *(const uint4*)(B + (size_t)(n0 + row) * Kp + kt + qq * 8);
            *(uint4*)(Bs + row * 40 + qq * 8) = vb;
        }
        __syncthreads();

        half8 af[4], bf[4];
#pragma unroll
        for (int mi = 0; mi < 4; ++mi)
            af[mi] = *(const half8*)(As + (wr * 64 + mi * 16 + c) * 40 + q * 8);
#pragma unroll
        for (int ni = 0; ni < 4; ++ni)
            bf[ni] = *(const half8*)(Bs + (wc * 64 + ni * 16 + c) * 40 + q * 8);
#pragma unroll
        for (int mi = 0; mi < 4; ++mi)
#pragma unroll
            for (int ni = 0; ni < 4; ++ni)
                acc[mi][ni] = __builtin_amdgcn_mfma_f32_16x16x32_f16(af[mi], bf[ni], acc[mi][ni], 0, 0, 0);
        __syncthreads();
    }

#pragma unroll
    for (int ni = 0; ni < 4; ++ni) {
        int n = n0 + wc * 64 + ni * 16 + c;
        float bv = bias[n];
#pragma unroll
        for (int mi = 0; mi < 4; ++mi) {
#pragma unroll
            for (int r = 0; r < 4; ++r) {
                int gm = m0 + wr * 64 + mi * 16 + q * 4 + r;
                if (gm < M) {
                    float v = acc[mi][ni][r] + bv;
                    if (use_f32) C32[(size_t)gm * NGATES + n] = v;
                    else         C16[(size_t)gm * NGATES + n] = (_Float16)v;
                }
            }
        }
    }
}

// ---------------- fused 2-layer persistent scan ----------------
// 16 WGs x 512 threads. WGs 0-7: layer-0 scan (64 feats each).
// WGs 8-15: layer-1 scan (64 feats each), consuming layer-0 rows via tagged H1T.
// Sync = tag-in-word polling only; NO barriers, NO counters, NO fences.
//
// LDS staging is frag-major: chunk for MFMA lane l=(q*16+c), k-slice ks lives
// at byte ks*1040 + l*16  (1040 = 1024 + 16B pad to break write-bank aliasing).
// ds_read_b128 of a-frags is then conflict-free (lane-consecutive 16B).

__device__ __forceinline__ void stage_tagged(const unsigned long long* __restrict__ src,
                                             unsigned tag, int j, char* lds) {
    const int b  = j >> 5;            // batch
    const int ks = (j & 31) >> 1;     // k-slice (feats 32*ks .. +31)
    const int q2 = (j & 1) * 2;       // first q-chunk of the two we write
    const unsigned long long* p = src + (size_t)j * 8;
    unsigned long long v[8];
    for (;;) {
        bool ok = true;
#pragma unroll
        for (int k = 0; k < 8; ++k)
            v[k] = __hip_atomic_load(p + k, __ATOMIC_RELAXED, __HIP_MEMORY_SCOPE_AGENT);
#pragma unroll
        for (int k = 0; k < 8; ++k)
            ok = ok & ((unsigned)(v[k] >> 32) == tag);
        if (ok) break;
    }
    uint32_t* l0 = (uint32_t*)(lds + ks * 1040 + (q2 * 16 + b) * 16);
    l0[0] = (uint32_t)v[0]; l0[1] = (uint32_t)v[1];
    l0[2] = (uint32_t)v[2]; l0[3] = (uint32_t)v[3];
    uint32_t* l1 = (uint32_t*)(lds + ks * 1040 + ((q2 + 1) * 16 + b) * 16);
    l1[0] = (uint32_t)v[4]; l1[1] = (uint32_t)v[5];
    l1[2] = (uint32_t)v[6]; l1[3] = (uint32_t)v[7];
}

__global__ __launch_bounds__(512, 1) void ligru_fused(
        const float* __restrict__ gates32, const _Float16* __restrict__ gates16,
        const _Float16* __restrict__ U0z, const _Float16* __restrict__ U0h,
        const _Float16* __restrict__ U1z, const _Float16* __restrict__ U1h,
        const _Float16* __restrict__ W1z, const _Float16* __restrict__ W1h,
        unsigned long long* __restrict__ exA,   // [2][EXW]
        unsigned long long* __restrict__ exC,   // [2][EXW]
        unsigned long long* __restrict__ H1T,   // [T_STEPS][EXW]
        const float* __restrict__ bh1, const float* __restrict__ bz1,
        float* __restrict__ out, int use_gf32) {

    __shared__ char ldsX[16 * 1040];                 // staging (A: h0-state; C: h1 rows)
    __shared__ char ldsY[16 * 1040];                 // staging (C: h2-state)
    __shared__ float accS[2][4][16][16];             // [gate][tile][feat16][batch]

    const int tid = threadIdx.x;
    const int l = tid & 63, wv = tid >> 6, q = l >> 4, c = l & 15;
    const int gate = wv >> 2, ti = wv & 3;           // 8 waves = 2 gates x 4 tiles
    const bool isA = (blockIdx.x < 8);
    const int wg = isA ? blockIdx.x : blockIdx.x - 8;
    const int fbase = wg * 64;

    // epilogue mapping: thread -> (batch, local feature pair)
    const int eb  = tid >> 5;
    const int fpl = tid & 31;
    const int f0  = 2 * fpl;                         // local feature (even)
    const int gf  = fbase + f0;                      // global feature
    const int eti = f0 >> 4, efi = f0 & 15;
    const int exi = eb * 256 + (fbase >> 1) + fpl;   // u64 index in a snapshot

    if (isA) {
        // ---- layer 0 ----
        const _Float16* U = (gate == 0) ? U0z : U0h;
        const int urow = fbase + ti * 16 + c;
        half8 u[16];
#pragma unroll
        for (int ks = 0; ks < 16; ++ks)
            u[ks] = *(const half8*)(U + (size_t)urow * HDIM + ks * 32 + q * 8);
#pragma unroll
        for (int ks = 0; ks < 16; ++ks)
            asm volatile("" : "+v"(u[ks]));

        float h0 = 0.f, h1 = 0.f;

        auto gload = [&](int t, float& w0, float& w1, float& z0, float& z1) {
            const int row = t * BATCH + eb;
            if (use_gf32) {
                float2 a2 = *(const float2*)(gates32 + (size_t)row * NGATES + gf);
                float2 b2 = *(const float2*)(gates32 + (size_t)row * NGATES + 512 + gf);
                w0 = a2.x; w1 = a2.y; z0 = b2.x; z1 = b2.y;
            } else {
                union { uint32_t u; _Float16 h[2]; } ua, ub;
                ua.u = *(const uint32_t*)(gates16 + (size_t)row * NGATES + gf);
                ub.u = *(const uint32_t*)(gates16 + (size_t)row * NGATES + 512 + gf);
                w0 = (float)ua.h[0]; w1 = (float)ua.h[1];
                z0 = (float)ub.h[0]; z1 = (float)ub.h[1];
            }
        };

        float whv0, whv1, wzv0, wzv1;
        gload(0, whv0, whv1, wzv0, wzv1);

        for (int t = 0; t < T_STEPS; ++t) {
            float nw0 = 0.f, nw1 = 0.f, nz0 = 0.f, nz1 = 0.f;
            if (t + 1 < T_STEPS) gload(t + 1, nw0, nw1, nz0, nz1);

            stage_tagged(exA + (size_t)(t & 1) * EXW, (unsigned)t, tid, ldsX);
            __syncthreads();

            floatx4 acc = {0.f, 0.f, 0.f, 0.f};
#pragma unroll
            for (int ks = 0; ks < 16; ++ks) {
                half8 a = *(const half8*)(ldsX + ks * 1040 + l * 16);
                acc = __builtin_amdgcn_mfma_f32_16x16x32_f16(a, u[ks], acc, 0, 0, 0);
            }
            *(floatx4*)&accS[gate][ti][c][q * 4] = acc;
            __syncthreads();

            float Sz0 = accS[0][eti][efi][eb],     Sh0 = accS[1][eti][efi][eb];
            float Sz1 = accS[0][eti][efi + 1][eb], Sh1 = accS[1][eti][efi + 1][eb];

            float z0 = 1.f / (1.f + __expf(-(wzv0 + Sz0)));
            float z1 = 1.f / (1.f + __expf(-(wzv1 + Sz1)));
            float hc0 = fmaxf(0.f, whv0 + Sh0);
            float hc1 = fmaxf(0.f, whv1 + Sh1);
            h0 = z0 * h0 + (1.f - z0) * hc0;
            h1 = z1 * h1 + (1.f - z1) * hc1;

            union { _Float16 h[2]; uint32_t u; } pk;
            pk.h[0] = (_Float16)h0; pk.h[1] = (_Float16)h1;
            unsigned long long tg = ((unsigned long long)(unsigned)(t + 1) << 32) | pk.u;
            __hip_atomic_store(exA + (size_t)((t + 1) & 1) * EXW + exi, tg,
                               __ATOMIC_RELAXED, __HIP_MEMORY_SCOPE_AGENT);
            __hip_atomic_store(H1T + (size_t)t * EXW + exi, tg,
                               __ATOMIC_RELAXED, __HIP_MEMORY_SCOPE_AGENT);

            whv0 = nw0; whv1 = nw1; wzv0 = nz0; wzv1 = nz1;
        }
    } else {
        // ---- layer 1 (input projection folded in) ----
        const _Float16* Wm = (gate == 0) ? W1z : W1h;
        const _Float16* Um = (gate == 0) ? U1z : U1h;
        const int urow = fbase + ti * 16 + c;
        half8 w[16], u[16];
#pragma unroll
        for (int ks = 0; ks < 16; ++ks) {
            w[ks] = *(const half8*)(Wm + (size_t)urow * HDIM + ks * 32 + q * 8);
            u[ks] = *(const half8*)(Um + (size_t)urow * HDIM + ks * 32 + q * 8);
        }
#pragma unroll
        for (int ks = 0; ks < 16; ++ks) {
            asm volatile("" : "+v"(w[ks]));
            asm volatile("" : "+v"(u[ks]));
        }

        const float bzv0 = bz1[gf], bzv1 = bz1[gf + 1];
        const float bhv0 = bh1[gf], bhv1 = bh1[gf + 1];
        float h0 = 0.f, h1 = 0.f;

        for (int t = 0; t < T_STEPS; ++t) {
            stage_tagged(H1T + (size_t)t * EXW, (unsigned)(t + 1), tid, ldsX);  // layer-0 out
            stage_tagged(exC + (size_t)(t & 1) * EXW, (unsigned)t, tid, ldsY);  // own state
            __syncthreads();

            floatx4 acc = {0.f, 0.f, 0.f, 0.f};
#pragma unroll
            for (int ks = 0; ks < 16; ++ks) {
                half8 a = *(const half8*)(ldsX + ks * 1040 + l * 16);
                acc = __builtin_amdgcn_mfma_f32_16x16x32_f16(a, w[ks], acc, 0, 0, 0);
            }
#pragma unroll
            for (int ks = 0; ks < 16; ++ks) {
                half8 a = *(const half8*)(ldsY + ks * 1040 + l * 16);
                acc = __builtin_amdgcn_mfma_f32_16x16x32_f16(a, u[ks], acc, 0, 0, 0);
            }
            *(floatx4*)&accS[gate][ti][c][q * 4] = acc;
            __syncthreads();

            float Sz0 = accS[0][eti][efi][eb],     Sh0 = accS[1][eti][efi][eb];
            float Sz1 = accS[0][eti][efi + 1][eb], Sh1 = accS[1][eti][efi + 1][eb];

            float z0 = 1.f / (1.f + __expf(-(bzv0 + Sz0)));
            float z1 = 1.f / (1.f + __expf(-(bzv1 + Sz1)));
            float hc0 = fmaxf(0.f, bhv0 + Sh0);
            float hc1 = fmaxf(0.f, bhv1 + Sh1);
            h0 = z0 * h0 + (1.f - z0) * hc0;
            h1 = z1 * h1 + (1.f - z1) * hc1;

            union { _Float16 h[2]; uint32_t u; } pk;
            pk.h[0] = (_Float16)h0; pk.h[1] = (_Float16)h1;
            unsigned long long tg = ((unsigned long long)(unsigned)(t + 1) << 32) | pk.u;
            __hip_atomic_store(exC + (size_t)((t + 1) & 1) * EXW + exi, tg,
                               __ATOMIC_RELAXED, __HIP_MEMORY_SCOPE_AGENT);

            float2 o; o.x = h0; o.y = h1;
            *(float2*)(out + (size_t)(t * BATCH + eb) * HDIM + gf) = o;   // final output
        }
    }
}

// ---------------- host ----------------

extern "C" void kernel_launch(void* const* d_in, const int* in_sizes, int n_in,
                              void* d_out, int out_size, void* d_ws, size_t ws_size,
                              hipStream_t stream) {
    const float* x   = (const float*)d_in[0];
    const float* Wh0 = (const float*)d_in[1];
    const float* bh0 = (const float*)d_in[2];
    const float* Wz0 = (const float*)d_in[3];
    const float* bz0 = (const float*)d_in[4];
    const float* Uh0 = (const float*)d_in[5];
    const float* Uz0 = (const float*)d_in[6];
    const float* Wh1 = (const float*)d_in[7];
    const float* bh1 = (const float*)d_in[8];
    const float* Wz1 = (const float*)d_in[9];
    const float* bz1 = (const float*)d_in[10];
    const float* Uh1 = (const float*)d_in[11];
    const float* Uz1 = (const float*)d_in[12];
    float* out = (float*)d_out;

    uint8_t* ws = (uint8_t*)d_ws;
    size_t off = 0;
    auto alloc = [&](size_t b) { size_t o = off; off += (b + 255) & ~(size_t)255; return o; };

    const size_t EXB  = (size_t)EXW * 8;                 // 32 KB per snapshot
    const size_t H1TB = (size_t)T_STEPS * EXW * 8;       // 48 MB tagged layer-0 outputs
    size_t o_tag  = alloc(2 * EXB + 2 * EXB + H1TB);     // exA[2] | exC[2] | H1T
    size_t o_U0z  = alloc((size_t)HDIM * HDIM * 2);
    size_t o_U0h  = alloc((size_t)HDIM * HDIM * 2);
    size_t o_U1z  = alloc((size_t)HDIM * HDIM * 2);
    size_t o_U1h  = alloc((size_t)HDIM * HDIM * 2);
    size_t o_W1z  = alloc((size_t)HDIM * HDIM * 2);
    size_t o_W1h  = alloc((size_t)HDIM * HDIM * 2);
    size_t o_Wc0  = alloc((size_t)NGATES * FPAD * 2);
    size_t o_b0   = alloc(1024 * 4);
    size_t o_xb   = alloc((size_t)MROWS * FPAD * 2);
    size_t o_g    = off;
    size_t need32 = off + (size_t)MROWS * NGATES * 4;
    int use_gf32 = (ws_size >= need32) ? 1 : 0;          // f16 gate fallback if tight

    unsigned long long* exA = (unsigned long long*)(ws + o_tag);
    unsigned long long* exC = exA + 2 * EXW;
    unsigned long long* H1T = exC + 2 * EXW;
    _Float16* U0Z = (_Float16*)(ws + o_U0z);
    _Float16* U0H = (_Float16*)(ws + o_U0h);
    _Float16* U1Z = (_Float16*)(ws + o_U1z);
    _Float16* U1H = (_Float16*)(ws + o_U1h);
    _Float16* W1Z = (_Float16*)(ws + o_W1z);
    _Float16* W1H = (_Float16*)(ws + o_W1h);
    _Float16* WC0 = (_Float16*)(ws + o_Wc0);
    float*    B0  = (float*)(ws + o_b0);
    _Float16* XB  = (_Float16*)(ws + o_xb);
    float*    G32 = (float*)(ws + o_g);
    _Float16* G16 = (_Float16*)(ws + o_g);

    // zero all tagged exchange state (tag 0 == initial h == 0); graph-capture-safe
    hipMemsetAsync(ws + o_tag, 0, 4 * EXB + H1TB, stream);

    // fp32 -> fp16 conversions (with K padding for layer-0 GEMM)
    cvt_pad<<<MROWS, 256, 0, stream>>>(x, XB, FDIM, FPAD);
    cvt_pad<<<512, 256, 0, stream>>>(Wh0, WC0,              FDIM, FPAD);
    cvt_pad<<<512, 256, 0, stream>>>(Wz0, WC0 + 512 * FPAD, FDIM, FPAD);
    cvt_pad<<<512, 256, 0, stream>>>(Uz0, U0Z, HDIM, HDIM);
    cvt_pad<<<512, 256, 0, stream>>>(Uh0, U0H, HDIM, HDIM);
    cvt_pad<<<512, 256, 0, stream>>>(Uz1, U1Z, HDIM, HDIM);
    cvt_pad<<<512, 256, 0, stream>>>(Uh1, U1H, HDIM, HDIM);
    cvt_pad<<<512, 256, 0, stream>>>(Wz1, W1Z, HDIM, HDIM);
    cvt_pad<<<512, 256, 0, stream>>>(Wh1, W1H, HDIM, HDIM);
    cat2<<<4, 256, 0, stream>>>(bh0, bz0, B0);

    // layer-0 gates GEMM (layer-1 projection is folded into the scan)
    dim3 gg(NGATES / 128, (MROWS + 127) / 128);
    gemm_tn<<<gg, 256, 0, stream>>>(XB, WC0, B0, G32, G16, MROWS, FPAD, use_gf32);

    // fused 2-layer pipelined persistent scan
    ligru_fused<<<16, 512, 0, stream>>>(G32, G16, U0Z, U0H, U1Z, U1H, W1Z, W1H,
                                        exA, exC, H1T, bh1, bz1, out, use_gf32);

    (void)in_sizes; (void)n_in; (void)out_size;
}